// Round 16
// baseline (326.968 us; speedup 1.0000x reference)
//
#include <hip/hip_runtime.h>
#include <hip/hip_bf16.h>

typedef __attribute__((ext_vector_type(8))) short short8;
typedef __attribute__((ext_vector_type(4))) float f32x4;
typedef __attribute__((ext_vector_type(16))) float f32x16;
typedef __attribute__((ext_vector_type(4))) int i32x4;
typedef unsigned short u16;

#define S_LEN 2048
#define D_DIM 2048
#define NHEAD 16
#define HDIM 128
#define M_ROWS 4096

#define MFMA(a,b,c) __builtin_amdgcn_mfma_f32_16x16x32_bf16(a,b,c,0,0,0)
#define MFMA32(a,b,c) __builtin_amdgcn_mfma_f32_32x32x16_bf16(a,b,c,0,0,0)

__device__ __forceinline__ u16 f2bf(float f) {
  union { float f; unsigned u; } v; v.f = f;
  unsigned r = v.u + 0x7fffu + ((v.u >> 16) & 1u);
  return (u16)(r >> 16);
}

__device__ __forceinline__ void async16(void* lds, const void* g) {
  __builtin_amdgcn_global_load_lds(
      (const __attribute__((address_space(1))) unsigned*)g,
      (__attribute__((address_space(3))) unsigned*)lds, 16, 0, 0);
}

__device__ __forceinline__ unsigned cvtpk(float lo, float hi) {
  unsigned r;
  asm("v_cvt_pk_bf16_f32 %0, %1, %2" : "=v"(r) : "v"(lo), "v"(hi));
  return r;
}
__device__ __forceinline__ void plswap(unsigned& x, unsigned& y) {
  asm("v_permlane32_swap_b32 %0, %1" : "+v"(x), "+v"(y));
}

// ---- fused prep: z<4 -> transpose+convert W_z; z=4,5 -> convert x ----
__global__ __launch_bounds__(256) void k_prep(const float* __restrict__ W0,
                                              const float* __restrict__ W1,
                                              const float* __restrict__ W2,
                                              const float* __restrict__ W3,
                                              u16* __restrict__ T0, u16* __restrict__ T1,
                                              u16* __restrict__ T2, u16* __restrict__ T3,
                                              const float* __restrict__ x,
                                              u16* __restrict__ xb) {
  const int z = blockIdx.z;
  if (z < 4) {
    __shared__ u16 tile[32][33];
    const float* W = (z == 0) ? W0 : (z == 1) ? W1 : (z == 2) ? W2 : W3;
    u16* Wt = (z == 0) ? T0 : (z == 1) ? T1 : (z == 2) ? T2 : T3;
    int n0 = blockIdx.x * 32, k0 = blockIdx.y * 32;
    int tx = threadIdx.x & 31, ty = threadIdx.x >> 5;
#pragma unroll
    for (int i = 0; i < 4; i++)
      tile[ty + i * 8][tx] = f2bf(W[(size_t)(k0 + ty + i * 8) * D_DIM + n0 + tx]);
    __syncthreads();
#pragma unroll
    for (int i = 0; i < 4; i++)
      Wt[(size_t)(n0 + ty + i * 8) * D_DIM + k0 + tx] = tile[tx][ty + i * 8];
  } else {
    const int row0 = (z - 4) * 2048 + blockIdx.y * 32;
    const int col0 = blockIdx.x * 32;
    const int r = threadIdx.x >> 3, c4 = threadIdx.x & 7;
    const float4 v = *reinterpret_cast<const float4*>(
        &x[(size_t)(row0 + r) * D_DIM + col0 + c4 * 4]);
    ushort4 o;
    o.x = f2bf(v.x); o.y = f2bf(v.y); o.z = f2bf(v.z); o.w = f2bf(v.w);
    *reinterpret_cast<ushort4*>(&xb[(size_t)(row0 + r) * D_DIM + col0 + c4 * 4]) = o;
  }
}

// ======== QKV: 256x256-tile 4-phase GEMM, class-local staging ========
// 8 waves (2M x 4N), wave tile 128x64, BK=64 as 2 K-subs of 32 (64B rows,
// slot^=(row>>1)&3 swizzle, proven conflict-free). LDS 128KB dbuf:
// per buf A[2 sub][256row][64B] 32KB + B same 32KB.
// CLASS-LOCAL STAGING: wave (wm=w>>2, bn=(w&3)>>1) stages A-half(wm) with
// its wm-group (4 waves x 4 loads) and B-half(bn) with its bn-group
// (4 loads) -> readers of every LDS region == its stagers. Tile top:
// lgkmcnt(0) + vmcnt(0) + barrier: each wave drains its OWN 8 loads, and
// since readers==stagers, all data any wave reads is resident. NO per-phase
// barriers (reads from buf, stages to nbuf). 1 barrier / 64 MFMA.
// Phase order (ms,ns) = (0,0),(0,1),(1,1),(1,0) minimizes live frags.
// Epilogue: Q,K scatter to [b,h,s,hd]; V direct to Vt[b,h,d,s].
__global__ __launch_bounds__(512, 1) void k_qkv(const u16* __restrict__ A,
                                                const u16* __restrict__ Bt,
                                                u16* __restrict__ outp,
                                                u16* __restrict__ Vt) {
  __shared__ __align__(16) char lds[131072];
  const int m0 = blockIdx.y * 256, n0 = blockIdx.x * 256;
  const int t = threadIdx.x;
  const int w = t >> 6, l = t & 63;
  const int wm = w >> 2, wn = w & 3, bn = wn >> 1;
  const int wr = wm * 128, wc = wn * 64;
  const int lr = l & 15, lq = l >> 4;
  const char* Ab = (const char*)A;
  const char* Bb = (const char*)Bt;

  // staging group indices
  const int gia = wn;                        // index within wm-group (0..3)
  const int gib = wm * 2 + (wn & 1);         // index within bn-group (0..3)

  f32x4 acc[8][4] = {};

  // stage half of A-half(wm): jpair selects K-sub s; covers rows wm*128..+127
  auto stageA = [&](int tt, int nb, int jpair) {
#pragma unroll
    for (int jj = 0; jj < 2; jj++) {
      const int s = jpair;          // K-sub
      const int rblk = jj;          // row block of 64
      const int row = wm * 128 + rblk * 64 + gia * 16 + (l >> 2);
      async16(lds + nb * 65536 + s * 16384 +
                  (wm * 128 + rblk * 64 + gia * 16) * 64 + l * 16,
              Ab + (size_t)(m0 + row) * 4096 + tt * 128 + s * 64 +
                  (((l & 3) ^ ((row >> 1) & 3)) * 16));
    }
  };
  auto stageB = [&](int tt, int nb, int jpair) {
#pragma unroll
    for (int jj = 0; jj < 2; jj++) {
      const int s = jpair;
      const int rblk = jj;
      const int row = bn * 128 + rblk * 64 + gib * 16 + (l >> 2);
      async16(lds + nb * 65536 + 32768 + s * 16384 +
                  (bn * 128 + rblk * 64 + gib * 16) * 64 + l * 16,
              Bb + (size_t)(n0 + row) * 4096 + tt * 128 + s * 64 +
                  (((l & 3) ^ ((row >> 1) & 3)) * 16));
    }
  };

  auto readA = [&](short8 af[4][2], int buf, int ms) {
#pragma unroll
    for (int mi = 0; mi < 4; mi++)
#pragma unroll
      for (int ks = 0; ks < 2; ks++) {
        const int row = wr + ms * 64 + mi * 16 + lr;
        af[mi][ks] = *reinterpret_cast<const short8*>(
            lds + buf * 65536 + ks * 16384 + row * 64 +
            ((lq ^ ((row >> 1) & 3)) * 16));
      }
  };
  auto readB = [&](short8 bf[2][2], int buf, int ns) {
#pragma unroll
    for (int ni = 0; ni < 2; ni++)
#pragma unroll
      for (int ks = 0; ks < 2; ks++) {
        const int row = wc + ns * 32 + ni * 16 + lr;
        bf[ni][ks] = *reinterpret_cast<const short8*>(
            lds + buf * 65536 + 32768 + ks * 16384 + row * 64 +
            ((lq ^ ((row >> 1) & 3)) * 16));
      }
  };

#define QUAD16(AF, BF, MS, NS)                                              \
  {                                                                         \
    __builtin_amdgcn_s_setprio(1);                                          \
    _Pragma("unroll") for (int mi = 0; mi < 4; mi++)                        \
    _Pragma("unroll") for (int ni = 0; ni < 2; ni++)                        \
    _Pragma("unroll") for (int ks = 0; ks < 2; ks++)                        \
      acc[(MS)*4 + mi][(NS)*2 + ni] =                                       \
          MFMA(AF[mi][ks], BF[ni][ks], acc[(MS)*4 + mi][(NS)*2 + ni]);      \
    __builtin_amdgcn_s_setprio(0);                                          \
  }

  // prologue: tile 0 -> buf 0 (8 own loads)
  stageA(0, 0, 0); stageA(0, 0, 1);
  stageB(0, 0, 0); stageB(0, 0, 1);

  short8 af0[4][2], af1[4][2], bf0[2][2], bf1[2][2];
  const int NT = D_DIM / 64;  // 32
  for (int tt = 0; tt < NT; tt++) {
    const int buf = tt & 1, nb = buf ^ 1;
    const bool pf = (tt + 1 < NT);
    // tile top: own ds_reads consumed + own DMA drained + block sync
    asm volatile("s_waitcnt lgkmcnt(0)" ::: "memory");
    asm volatile("s_waitcnt vmcnt(0)" ::: "memory");
    __builtin_amdgcn_s_barrier();
    asm volatile("" ::: "memory");
    // phase 0: (ms0, ns0)
    if (pf) stageA(tt + 1, nb, 0);
    readA(af0, buf, 0); readB(bf0, buf, 0);
    QUAD16(af0, bf0, 0, 0);
    // phase 1: (ms0, ns1)
    if (pf) stageA(tt + 1, nb, 1);
    readB(bf1, buf, 1);
    QUAD16(af0, bf1, 0, 1);
    // phase 2: (ms1, ns1)
    if (pf) stageB(tt + 1, nb, 0);
    readA(af1, buf, 1);
    QUAD16(af1, bf1, 1, 1);
    // phase 3: (ms1, ns0)
    if (pf) stageB(tt + 1, nb, 1);
    QUAD16(af1, bf0, 1, 0);
  }
#undef QUAD16

  // epilogue: Q,K scatter; V -> Vt[b,h,d,s] direct
#pragma unroll
  for (int gm = 0; gm < 8; gm++) {
#pragma unroll
    for (int gn = 0; gn < 4; gn++) {
      const int row0 = m0 + wr + gm * 16 + lq * 4;
      const int col = n0 + wc + gn * 16 + lr;
      if (col >= 4096) {
        const int d = col & 127, hh = (col >> 7) & 15;
        const int bb = row0 >> 11, s0 = row0 & 2047;
        ushort4 v4;
        v4.x = f2bf(acc[gm][gn][0]);
        v4.y = f2bf(acc[gm][gn][1]);
        v4.z = f2bf(acc[gm][gn][2]);
        v4.w = f2bf(acc[gm][gn][3]);
        *reinterpret_cast<ushort4*>(
            Vt + (((size_t)(bb * NHEAD + hh) * HDIM + d) * S_LEN + s0)) = v4;
      } else {
#pragma unroll
        for (int r = 0; r < 4; r++) {
          const int row = row0 + r;
          const int mat = col >> 11;
          const int hh = (col >> 7) & 15;
          outp[(size_t)mat * 8388608 +
               (((size_t)((row >> 11) * NHEAD + hh)) * S_LEN + (row & 2047)) * HDIM +
               (col & 127)] = f2bf(acc[gm][gn][r]);
        }
      }
    }
  }
}

// ======== O-proj: R9-proven 128x256 4-phase dbuf GEMM ========
__global__ __launch_bounds__(512, 1) void k_oproj(const u16* __restrict__ A,
                                                  const u16* __restrict__ Bt,
                                                  float* __restrict__ outp,
                                                  const float* __restrict__ fac) {
  constexpr int BUFSZ = 49152;
  __shared__ __align__(16) char lds[2 * 49152];
  const int m0 = blockIdx.y * 128, n0 = blockIdx.x * 256;
  const int t = threadIdx.x;
  const int w = t >> 6, l = t & 63;
  const int wr = (w >> 2) * 64, wc = (w & 3) * 64;
  const int lr = l & 15, lq = l >> 4;
  const char* Ab = (const char*)A;
  const char* Bb = (const char*)Bt;

  f32x4 acc[4][4] = {};

  const int sub = w >> 2, ww = w & 3;
  const int abase = (ww & 1) * 16 + (ww >> 1) * 64;
  const int bbase = (w >> 1) * 64 + (w & 1) * 16;
  const int rr = l >> 2, sl = l & 3;

  auto stageA = [&](int tt, int nb, int mh) {
    const int base = abase + mh * 32;
    const int row = base + rr;
    async16(lds + nb * BUFSZ + sub * 8192 + base * 64,
            Ab + (size_t)(m0 + row) * 4096 + tt * 128 + sub * 64 +
                ((sl ^ ((row >> 1) & 3)) * 16));
  };
  auto stageB = [&](int tt, int nb, int nh) {
    const int base = bbase + nh * 32;
    const int row = base + rr;
#pragma unroll
    for (int j = 0; j < 2; j++)
      async16(lds + nb * BUFSZ + 16384 + j * 16384 + base * 64,
              Bb + (size_t)(n0 + row) * 4096 + tt * 128 + j * 64 +
                  ((sl ^ ((row >> 1) & 3)) * 16));
  };
  auto readA = [&](short8 af[2][2], int buf, int mh) {
#pragma unroll
    for (int mi = 0; mi < 2; mi++)
#pragma unroll
      for (int ks = 0; ks < 2; ks++) {
        const int row = wr + mh * 32 + mi * 16 + lr;
        af[mi][ks] = *reinterpret_cast<const short8*>(
            lds + buf * BUFSZ + ks * 8192 + row * 64 +
            ((lq ^ ((row >> 1) & 3)) * 16));
      }
  };
  auto readB = [&](short8 bf[2][2], int buf, int nh) {
#pragma unroll
    for (int ni = 0; ni < 2; ni++)
#pragma unroll
      for (int ks = 0; ks < 2; ks++) {
        const int row = wc + nh * 32 + ni * 16 + lr;
        bf[ni][ks] = *reinterpret_cast<const short8*>(
            lds + buf * BUFSZ + 16384 + ks * 16384 + row * 64 +
            ((lq ^ ((row >> 1) & 3)) * 16));
      }
  };

#define QUAD(AF, BF, MH, NH)                                                \
  {                                                                         \
    __builtin_amdgcn_s_setprio(1);                                          \
    _Pragma("unroll") for (int mi = 0; mi < 2; mi++)                        \
    _Pragma("unroll") for (int ni = 0; ni < 2; ni++)                        \
    _Pragma("unroll") for (int ks = 0; ks < 2; ks++)                        \
      acc[(MH)*2 + mi][(NH)*2 + ni] =                                       \
          MFMA(AF[mi][ks], BF[ni][ks], acc[(MH)*2 + mi][(NH)*2 + ni]);      \
    __builtin_amdgcn_s_setprio(0);                                          \
  }
#define VMW(N) asm volatile("s_waitcnt vmcnt(" #N ")" ::: "memory")
#define BAR()                         \
  do {                                \
    __builtin_amdgcn_s_barrier();     \
    asm volatile("" ::: "memory");    \
  } while (0)

  stageA(0, 0, 0); stageB(0, 0, 0);
  stageA(0, 0, 1);
  stageB(0, 0, 1);

  short8 af0[2][2], af1[2][2], bfr[2][2];
  const int NT = D_DIM / 64;
  for (int tt = 0; tt < NT; tt++) {
    const int buf = tt & 1, nb = buf ^ 1;
    const bool pf = (tt + 1 < NT);
    VMW(3); BAR();
    if (pf) { stageA(tt + 1, nb, 0); stageB(tt + 1, nb, 0); }
    readA(af0, buf, 0); readB(bfr, buf, 0);
    QUAD(af0, bfr, 0, 0);
    if (pf) VMW(5); else VMW(2);
    BAR();
    if (pf) stageA(tt + 1, nb, 1);
    readA(af1, buf, 1);
    QUAD(af1, bfr, 1, 0);
    if (pf) VMW(4); else VMW(0);
    BAR();
    if (pf) stageB(tt + 1, nb, 1);
    readB(bfr, buf, 1);
    QUAD(af1, bfr, 1, 1);
    BAR();
    QUAD(af0, bfr, 0, 1);
  }
#undef QUAD
#undef VMW
#undef BAR

#pragma unroll
  for (int gm = 0; gm < 4; gm++) {
#pragma unroll
    for (int gn = 0; gn < 4; gn++) {
      const int row0 = m0 + wr + gm * 16 + lq * 4;
      const int col = n0 + wc + gn * 16 + lr;
#pragma unroll
      for (int r = 0; r < 4; r++) {
        const int row = row0 + r;
        outp[(size_t)row * D_DIM + col] =
            acc[gm][gn][r] * (1.0f + 0.1f * fac[row]);
      }
    }
  }
}

// -------- phase projections pq/pk = xb @ Wpq / xb @ Wpk --------
__global__ __launch_bounds__(256) void k_phase_proj(const u16* __restrict__ xb,
                                                    const float* __restrict__ Wpq,
                                                    const float* __restrict__ Wpk,
                                                    float* __restrict__ pq,
                                                    float* __restrict__ pk) {
  __shared__ u16 xs[16][136];
  __shared__ float2 ws[128][16];
  const int t = threadIdx.x;
  const int m0 = blockIdx.x * 16;
  const int h = t & 15, r = t >> 4;
  float sq = 0.f, sk = 0.f;
  for (int kc = 0; kc < D_DIM; kc += 128) {
    *reinterpret_cast<short8*>(&xs[t >> 4][(t & 15) * 8]) =
        *reinterpret_cast<const short8*>(
            &xb[(size_t)(m0 + (t >> 4)) * D_DIM + kc + (t & 15) * 8]);
#pragma unroll
    for (int j = 0; j < 8; j++) {
      const int idx = j * 256 + t;
      const int k = idx >> 4, hh = idx & 15;
      ws[k][hh] = make_float2(Wpq[(size_t)(kc + k) * NHEAD + hh],
                              Wpk[(size_t)(kc + k) * NHEAD + hh]);
    }
    __syncthreads();
#pragma unroll
    for (int k8 = 0; k8 < 16; k8++) {
      const short8 x8 = *reinterpret_cast<const short8*>(&xs[r][k8 * 8]);
#pragma unroll
      for (int j = 0; j < 8; j++) {
        union { float f; unsigned u; } c;
        c.u = ((unsigned)(u16)x8[j]) << 16;
        const float2 wv = ws[k8 * 8 + j][h];
        sq += c.f * wv.x;
        sk += c.f * wv.y;
      }
    }
    __syncthreads();
  }
  pq[(size_t)(m0 + r) * NHEAD + h] = sq;
  pk[(size_t)(m0 + r) * NHEAD + h] = sk;
}

__device__ __forceinline__ float wave_sum(float v) {
  v += __shfl_xor(v, 1);  v += __shfl_xor(v, 2);  v += __shfl_xor(v, 4);
  v += __shfl_xor(v, 8);  v += __shfl_xor(v, 16); v += __shfl_xor(v, 32);
  return v;
}

// -------- Ck/Sk = sum_s cos/sin(pk) per (b,h) --------
__global__ void k_phase_ck(const float* __restrict__ pk, float* __restrict__ Ck,
                           float* __restrict__ Sk) {
  int bh = blockIdx.x, b = bh >> 4, h = bh & 15;
  float c = 0.f, s = 0.f;
  for (int ss = threadIdx.x; ss < S_LEN; ss += 256) {
    float v = pk[((size_t)b * S_LEN + ss) * NHEAD + h];
    c += cosf(v); s += sinf(v);
  }
  c = wave_sum(c); s = wave_sum(s);
  __shared__ float rc[4], rs[4];
  int wv = threadIdx.x >> 6;
  if ((threadIdx.x & 63) == 0) { rc[wv] = c; rs[wv] = s; }
  __syncthreads();
  if (threadIdx.x == 0) {
    Ck[bh] = rc[0] + rc[1] + rc[2] + rc[3];
    Sk[bh] = rs[0] + rs[1] + rs[2] + rs[3];
  }
}

// -------- phase_mod[m] --------
__global__ void k_phase_mod(const float* __restrict__ pq, const float* __restrict__ Ck,
                            const float* __restrict__ Sk, float* __restrict__ pm) {
  int m = blockIdx.x * 256 + threadIdx.x;
  int b = m >> 11;
  float a = 0.f;
#pragma unroll
  for (int h = 0; h < NHEAD; h++) {
    float v = pq[(size_t)m * NHEAD + h];
    a += cosf(v) * Ck[b * NHEAD + h] + sinf(v) * Sk[b * NHEAD + h];
  }
  pm[m] = a * (1.0f / (S_LEN * NHEAD));
}

// -------- causal flash attention: R5-proven serial-staged loop --------
__global__ __launch_bounds__(256, 2) void k_attn(const u16* __restrict__ Q,
                                                 const u16* __restrict__ K,
                                                 const u16* __restrict__ Vt,
                                                 u16* __restrict__ ctx) {
  const int bh = blockIdx.x;
  const int gy = blockIdx.y;
  const int g = (gy < 8) ? (15 - gy) : (gy - 8);
  const int b = bh >> 4, h = bh & 15;
  const int t = threadIdx.x;
  const int w = t >> 6, l = t & 63;
  const int ln = l & 31, hi = l >> 5;
  const int q0w = g * 128 + w * 32;
  const int qq = q0w + ln;
  const float sc2 = 0.08838834764831845f * 1.4426950408889634f;

  const u16* Qp = Q + (size_t)bh * S_LEN * HDIM;
  const char* Kg = (const char*)(K + (size_t)bh * S_LEN * HDIM);
  const char* Vg = (const char*)(Vt + (size_t)bh * HDIM * S_LEN);

  __shared__ __align__(16) char Ks[16384];
  __shared__ __align__(16) char Vs[16384];

  auto stage = [&](int t64) {
    const int k0 = t64 * 64;
#pragma unroll
    for (int i = 0; i < 4; i++) {
      const int key = i * 16 + w * 4 + (l >> 4);
      async16(Ks + i * 4096 + w * 1024,
              Kg + (size_t)(k0 + key) * 256 + (((l & 15) * 16) ^ ((key & 15) << 4)));
      const int d = i * 32 + w * 8 + (l >> 3);
      async16(Vs + i * 4096 + w * 1024,
              Vg + (size_t)d * (S_LEN * 2) + k0 * 2 + (((l & 7) * 16) ^ ((d & 7) << 4)));
    }
  };

  short8 qf[8];
#pragma unroll
  for (int c = 0; c < 8; c++)
    qf[c] = *reinterpret_cast<const short8*>(Qp + (size_t)qq * HDIM + c * 16 + hi * 8);

  f32x16 o[4];
#pragma unroll
  for (int ds = 0; ds < 4; ds++)
#pragma unroll
    for (int r = 0; r < 16; r++) o[ds][r] = 0.f;
  float mrun = -1e30f, lsum = 0.f;

  const int nt = (g + 1) * 2;
  for (int t64 = 0; t64 < nt; t64++) {
    const int k0 = t64 * 64;
    stage(t64);
    __syncthreads();
    if (k0 < q0w + 32) {
      f32x16 s[2];
#pragma unroll
      for (int ks = 0; ks < 2; ks++)
#pragma unroll
        for (int r = 0; r < 16; r++) s[ks][r] = 0.f;
      __builtin_amdgcn_s_setprio(1);
#pragma unroll
      for (int ks = 0; ks < 2; ks++) {
        const int key = ks * 32 + ln;
        const char* kb = Ks + key * 256;
        const unsigned swzk = (unsigned)((key & 15) << 4);
#pragma unroll
        for (int c = 0; c < 8; c++) {
          const short8 kf = *reinterpret_cast<const short8*>(
              kb + (((unsigned)(c * 32 + hi * 16)) ^ swzk));
          s[ks] = MFMA32(kf, qf[c], s[ks]);
        }
      }
      __builtin_amdgcn_s_setprio(0);
      float p[32];
      float mx = -1e30f;
      const bool interior = (k0 + 64 <= q0w + 1);
      if (interior) {
#pragma unroll
        for (int ks = 0; ks < 2; ks++)
#pragma unroll
          for (int r = 0; r < 16; r++) {
            const float v = s[ks][r] * sc2;
            p[ks * 16 + r] = v;
            mx = fmaxf(mx, v);
          }
      } else {
#pragma unroll
        for (int ks = 0; ks < 2; ks++)
#pragma unroll
          for (int r = 0; r < 16; r++) {
            const int key = k0 + ks * 32 + (r & 3) + 8 * (r >> 2) + 4 * hi;
            const float v = (key <= qq) ? s[ks][r] * sc2 : -1e30f;
            p[ks * 16 + r] = v;
            mx = fmaxf(mx, v);
          }
      }
      mx = fmaxf(mx, __shfl_xor(mx, 32));
      if (!__all(mx <= mrun + 11.0f)) {
        const float nm = fmaxf(mrun, mx);
        const float f = exp2f(mrun - nm);
        lsum *= f;
#pragma unroll
        for (int ds = 0; ds < 4; ds++)
#pragma unroll
          for (int r = 0; r < 16; r++) o[ds][r] *= f;
        mrun = nm;
      }
      float rs = 0.f;
#pragma unroll
      for (int i = 0; i < 32; i++) { p[i] = exp2f(p[i] - mrun); rs += p[i]; }
      rs += __shfl_xor(rs, 32);
      lsum += rs;
      short8 bfr[4];
#pragma unroll
      for (int sub = 0; sub < 2; sub++) {
#pragma unroll
        for (int half = 0; half < 2; half++) {
          const int pb = sub * 16 + half * 8;
          unsigned X1 = cvtpk(p[pb + 0], p[pb + 1]);
          unsigned X2 = cvtpk(p[pb + 2], p[pb + 3]);
          unsigned Y1 = cvtpk(p[pb + 4], p[pb + 5]);
          unsigned Y2 = cvtpk(p[pb + 6], p[pb + 7]);
          plswap(X1, Y1);
          plswap(X2, Y2);
          i32x4 bw;
          bw[0] = (int)X1; bw[1] = (int)X2; bw[2] = (int)Y1; bw[3] = (int)Y2;
          bfr[sub * 2 + half] = __builtin_bit_cast(short8, bw);
        }
      }
      __builtin_amdgcn_s_setprio(1);
#pragma unroll
      for (int ds = 0; ds < 4; ds++) {
        const int d = ds * 32 + ln;
        const char* vb = Vs + d * 128;
        const unsigned swzv = (unsigned)((d & 7) << 4);
#pragma unroll
        for (int slot = 0; slot < 4; slot++) {
          const short8 vf = *reinterpret_cast<const short8*>(
              vb + (((unsigned)(slot * 32 + hi * 16)) ^ swzv));
          o[ds] = MFMA32(vf, bfr[slot], o[ds]);
        }
      }
      __builtin_amdgcn_s_setprio(0);
    }
    __syncthreads();
  }

  const float rl = 1.0f / lsum;
#pragma unroll
  for (int ds = 0; ds < 4; ds++) {
#pragma unroll
    for (int rq = 0; rq < 4; rq++) {
      const int d = ds * 32 + 8 * rq + 4 * hi;
      ushort4 pk4;
      pk4.x = f2bf(o[ds][rq * 4 + 0] * rl);
      pk4.y = f2bf(o[ds][rq * 4 + 1] * rl);
      pk4.z = f2bf(o[ds][rq * 4 + 2] * rl);
      pk4.w = f2bf(o[ds][rq * 4 + 3] * rl);
      *reinterpret_cast<ushort4*>(ctx + ((size_t)(b * S_LEN + qq)) * D_DIM + h * HDIM + d) = pk4;
    }
  }
}

extern "C" void kernel_launch(void* const* d_in, const int* in_sizes, int n_in,
                              void* d_out, int out_size, void* d_ws, size_t ws_size,
                              hipStream_t stream) {
  const float* x   = (const float*)d_in[0];
  const float* Wq  = (const float*)d_in[1];
  const float* Wk  = (const float*)d_in[2];
  const float* Wv  = (const float*)d_in[3];
  const float* Wo  = (const float*)d_in[4];
  const float* Wpq = (const float*)d_in[5];
  const float* Wpk = (const float*)d_in[6];

  char* ws = (char*)d_ws;
  u16* xb   = (u16*)(ws + 0);
  u16* Wqt  = (u16*)(ws + 16777216);
  u16* Wkt  = (u16*)(ws + 25165824);
  u16* Wvt  = (u16*)(ws + 33554432);
  u16* Wot  = (u16*)(ws + 41943040);
  u16* Qb   = (u16*)(ws + 50331648);
  u16* Kb   = (u16*)(ws + 67108864);
  u16* Vb   = (u16*)(ws + 83886080);
  u16* Vt   = (u16*)(ws + 100663296);
  float* pq = (float*)(ws + 117440512);
  float* pk = (float*)(ws + 117702656);
  float* Ck = (float*)(ws + 117964800);
  float* Sk = (float*)(ws + 117964928);
  float* pm = (float*)(ws + 117965056);

  k_prep<<<dim3(64, 64, 6), 256, 0, stream>>>(Wq, Wk, Wv, Wo, Wqt, Wkt, Wvt, Wot, x, xb);

  // fused QKV: 256x256 tiles, grid 24x16 = 384 blocks
  k_qkv<<<dim3(24, 16), 512, 0, stream>>>(xb, Wqt, Qb, Vt);

  k_phase_proj<<<dim3(256), 256, 0, stream>>>(xb, Wpq, Wpk, pq, pk);
  k_phase_ck<<<dim3(32), 256, 0, stream>>>(pk, Ck, Sk);
  k_phase_mod<<<dim3(16), 256, 0, stream>>>(pq, Ck, Sk, pm);

  k_attn<<<dim3(32, 16), 256, 0, stream>>>(Qb, Kb, Vt, Vb /*ctx*/);

  // O-proj: 128x256 tiles, grid 8x32 = 256 blocks
  k_oproj<<<dim3(8, 32), 512, 0, stream>>>(Vb /*ctx*/, Wot, (float*)d_out, pm);
}

// Round 17
// 321.909 us; speedup vs baseline: 1.0157x; 1.0157x over previous
//
#include <hip/hip_runtime.h>
#include <hip/hip_bf16.h>

typedef __attribute__((ext_vector_type(8))) short short8;
typedef __attribute__((ext_vector_type(4))) float f32x4;
typedef __attribute__((ext_vector_type(16))) float f32x16;
typedef __attribute__((ext_vector_type(4))) int i32x4;
typedef unsigned short u16;

#define S_LEN 2048
#define D_DIM 2048
#define NHEAD 16
#define HDIM 128
#define M_ROWS 4096

#define MFMA(a,b,c) __builtin_amdgcn_mfma_f32_16x16x32_bf16(a,b,c,0,0,0)
#define MFMA32(a,b,c) __builtin_amdgcn_mfma_f32_32x32x16_bf16(a,b,c,0,0,0)

__device__ __forceinline__ u16 f2bf(float f) {
  union { float f; unsigned u; } v; v.f = f;
  unsigned r = v.u + 0x7fffu + ((v.u >> 16) & 1u);
  return (u16)(r >> 16);
}

__device__ __forceinline__ void async16(void* lds, const void* g) {
  __builtin_amdgcn_global_load_lds(
      (const __attribute__((address_space(1))) unsigned*)g,
      (__attribute__((address_space(3))) unsigned*)lds, 16, 0, 0);
}

__device__ __forceinline__ unsigned cvtpk(float lo, float hi) {
  unsigned r;
  asm("v_cvt_pk_bf16_f32 %0, %1, %2" : "=v"(r) : "v"(lo), "v"(hi));
  return r;
}
__device__ __forceinline__ void plswap(unsigned& x, unsigned& y) {
  asm("v_permlane32_swap_b32 %0, %1" : "+v"(x), "+v"(y));
}

// ---- fused prep: z<4 -> transpose+convert W_z; z=4,5 -> convert x ----
__global__ __launch_bounds__(256) void k_prep(const float* __restrict__ W0,
                                              const float* __restrict__ W1,
                                              const float* __restrict__ W2,
                                              const float* __restrict__ W3,
                                              u16* __restrict__ T0, u16* __restrict__ T1,
                                              u16* __restrict__ T2, u16* __restrict__ T3,
                                              const float* __restrict__ x,
                                              u16* __restrict__ xb) {
  const int z = blockIdx.z;
  if (z < 4) {
    __shared__ u16 tile[32][33];
    const float* W = (z == 0) ? W0 : (z == 1) ? W1 : (z == 2) ? W2 : W3;
    u16* Wt = (z == 0) ? T0 : (z == 1) ? T1 : (z == 2) ? T2 : T3;
    int n0 = blockIdx.x * 32, k0 = blockIdx.y * 32;
    int tx = threadIdx.x & 31, ty = threadIdx.x >> 5;
#pragma unroll
    for (int i = 0; i < 4; i++)
      tile[ty + i * 8][tx] = f2bf(W[(size_t)(k0 + ty + i * 8) * D_DIM + n0 + tx]);
    __syncthreads();
#pragma unroll
    for (int i = 0; i < 4; i++)
      Wt[(size_t)(n0 + ty + i * 8) * D_DIM + k0 + tx] = tile[tx][ty + i * 8];
  } else {
    const int row0 = (z - 4) * 2048 + blockIdx.y * 32;
    const int col0 = blockIdx.x * 32;
    const int r = threadIdx.x >> 3, c4 = threadIdx.x & 7;
    const float4 v = *reinterpret_cast<const float4*>(
        &x[(size_t)(row0 + r) * D_DIM + col0 + c4 * 4]);
    ushort4 o;
    o.x = f2bf(v.x); o.y = f2bf(v.y); o.z = f2bf(v.z); o.w = f2bf(v.w);
    *reinterpret_cast<ushort4*>(&xb[(size_t)(row0 + r) * D_DIM + col0 + c4 * 4]) = o;
  }
}

// ======== 4-phase dbuf GEMM (R9-proven): C = A[M][K] * Bt[N][K]^T ========
// Tile 128x256, BK=64 (2 K-subs), 8 waves (2M x 4N), wave tile 64x64.
// Counted vmcnt {3,5,4} steady / {3,2,0} tail (in-order retirement proof).
// 3 barriers/K-tile (phase-3 is pure-register MFMA; next tile-top VMW+BAR
// closes the window before any buffer reuse). MODE 0: scatter Q,K bf16 into
// [b,h,s,hd]; V written DIRECTLY into Vt[b,h,d,s]. MODE 1: f32 with factor.
template <int MODE>
__device__ __forceinline__ void gemm_body(const u16* __restrict__ A,
                                          const u16* __restrict__ Bt,
                                          void* __restrict__ outp,
                                          u16* __restrict__ Vt,
                                          const float* __restrict__ fac,
                                          char* lds) {
  constexpr int BUFSZ = 49152;  // A 2x8KB + B 2x16KB
  const int m0 = blockIdx.y * 128, n0 = blockIdx.x * 256;
  const int t = threadIdx.x;
  const int w = t >> 6, l = t & 63;
  const int wr = (w >> 2) * 64, wc = (w & 3) * 64;
  const int lr = l & 15, lq = l >> 4;
  const char* Ab = (const char*)A;
  const char* Bb = (const char*)Bt;

  f32x4 acc[4][4] = {};

  const int sub = w >> 2, ww = w & 3;
  const int abase = (ww & 1) * 16 + (ww >> 1) * 64;
  const int bbase = (w >> 1) * 64 + (w & 1) * 16;
  const int rr = l >> 2, sl = l & 3;

  auto stageA = [&](int tt, int nb, int mh) {
    const int base = abase + mh * 32;
    const int row = base + rr;
    async16(lds + nb * BUFSZ + sub * 8192 + base * 64,
            Ab + (size_t)(m0 + row) * 4096 + tt * 128 + sub * 64 +
                ((sl ^ ((row >> 1) & 3)) * 16));
  };
  auto stageB = [&](int tt, int nb, int nh) {
    const int base = bbase + nh * 32;
    const int row = base + rr;
#pragma unroll
    for (int j = 0; j < 2; j++)
      async16(lds + nb * BUFSZ + 16384 + j * 16384 + base * 64,
              Bb + (size_t)(n0 + row) * 4096 + tt * 128 + j * 64 +
                  ((sl ^ ((row >> 1) & 3)) * 16));
  };

  auto readA = [&](short8 af[2][2], int buf, int mh) {
#pragma unroll
    for (int mi = 0; mi < 2; mi++)
#pragma unroll
      for (int ks = 0; ks < 2; ks++) {
        const int row = wr + mh * 32 + mi * 16 + lr;
        af[mi][ks] = *reinterpret_cast<const short8*>(
            lds + buf * BUFSZ + ks * 8192 + row * 64 +
            ((lq ^ ((row >> 1) & 3)) * 16));
      }
  };
  auto readB = [&](short8 bf[2][2], int buf, int nh) {
#pragma unroll
    for (int ni = 0; ni < 2; ni++)
#pragma unroll
      for (int ks = 0; ks < 2; ks++) {
        const int row = wc + nh * 32 + ni * 16 + lr;
        bf[ni][ks] = *reinterpret_cast<const short8*>(
            lds + buf * BUFSZ + 16384 + ks * 16384 + row * 64 +
            ((lq ^ ((row >> 1) & 3)) * 16));
      }
  };

#define QUAD(AF, BF, MH, NH)                                                \
  {                                                                         \
    __builtin_amdgcn_s_setprio(1);                                          \
    _Pragma("unroll") for (int mi = 0; mi < 2; mi++)                        \
    _Pragma("unroll") for (int ni = 0; ni < 2; ni++)                        \
    _Pragma("unroll") for (int ks = 0; ks < 2; ks++)                        \
      acc[(MH)*2 + mi][(NH)*2 + ni] =                                       \
          MFMA(AF[mi][ks], BF[ni][ks], acc[(MH)*2 + mi][(NH)*2 + ni]);      \
    __builtin_amdgcn_s_setprio(0);                                          \
  }
#define VMW(N) asm volatile("s_waitcnt vmcnt(" #N ")" ::: "memory")
#define BAR()                         \
  do {                                \
    __builtin_amdgcn_s_barrier();     \
    asm volatile("" ::: "memory");    \
  } while (0)

  // prologue: u0, u1, u2 of tile 0 -> buf 0 (6 loads)
  stageA(0, 0, 0); stageB(0, 0, 0);
  stageA(0, 0, 1);
  stageB(0, 0, 1);

  short8 af0[2][2], af1[2][2], bfr[2][2];
  const int NT = D_DIM / 64;  // 32
  for (int tt = 0; tt < NT; tt++) {
    const int buf = tt & 1, nb = buf ^ 1;
    const bool pf = (tt + 1 < NT);
    // phase 0: (0,0); needs u0(t); stage u0(t+1)
    VMW(3); BAR();
    if (pf) { stageA(tt + 1, nb, 0); stageB(tt + 1, nb, 0); }
    readA(af0, buf, 0); readB(bfr, buf, 0);
    QUAD(af0, bfr, 0, 0);
    // phase 1: (1,0); needs u1(t); stage u1(t+1)
    if (pf) VMW(5); else VMW(2);
    BAR();
    if (pf) stageA(tt + 1, nb, 1);
    readA(af1, buf, 1);
    QUAD(af1, bfr, 1, 0);
    // phase 2: (1,1); needs u2(t); stage u2(t+1)
    if (pf) VMW(4); else VMW(0);
    BAR();
    if (pf) stageB(tt + 1, nb, 1);
    readB(bfr, buf, 1);
    QUAD(af1, bfr, 1, 1);
    // phase 3: (0,1); pure-register MFMA — no barrier needed (next tile-top
    // VMW+BAR closes the window before any buffer reuse)
    QUAD(af0, bfr, 0, 1);
  }
#undef QUAD
#undef VMW
#undef BAR

  // epilogue
#pragma unroll
  for (int gm = 0; gm < 4; gm++) {
#pragma unroll
    for (int gn = 0; gn < 4; gn++) {
      const int row0 = m0 + wr + gm * 16 + lq * 4;
      const int col = n0 + wc + gn * 16 + lr;
      if (MODE == 0) {
        if (col >= 4096) {  // V -> Vt[b,h,d,s] direct (s-consecutive r's)
          const int d = col & 127, hh = (col >> 7) & 15;
          const int bb = row0 >> 11, s0 = row0 & 2047;
          ushort4 v4;
          v4.x = f2bf(acc[gm][gn][0]);
          v4.y = f2bf(acc[gm][gn][1]);
          v4.z = f2bf(acc[gm][gn][2]);
          v4.w = f2bf(acc[gm][gn][3]);
          *reinterpret_cast<ushort4*>(
              Vt + (((size_t)(bb * NHEAD + hh) * HDIM + d) * S_LEN + s0)) = v4;
        } else {
#pragma unroll
          for (int r = 0; r < 4; r++) {
            const int row = row0 + r;
            const int mat = col >> 11;
            const int hh = (col >> 7) & 15;
            ((u16*)outp)[(size_t)mat * 8388608 +
                         (((size_t)((row >> 11) * NHEAD + hh)) * S_LEN + (row & 2047)) * HDIM +
                         (col & 127)] = f2bf(acc[gm][gn][r]);
          }
        }
      } else {
#pragma unroll
        for (int r = 0; r < 4; r++) {
          const int row = row0 + r;
          ((float*)outp)[(size_t)row * D_DIM + col] = acc[gm][gn][r] * fac[row];
        }
      }
    }
  }
}

__global__ __launch_bounds__(512, 1) void k_qkv(const u16* __restrict__ A,
                                                const u16* __restrict__ Bt,
                                                void* __restrict__ outp,
                                                u16* __restrict__ Vt) {
  __shared__ __align__(16) char lds[2 * 49152];
  gemm_body<0>(A, Bt, outp, Vt, nullptr, lds);
}

__global__ __launch_bounds__(512, 1) void k_oproj(const u16* __restrict__ A,
                                                  const u16* __restrict__ Bt,
                                                  void* __restrict__ outp,
                                                  const float* __restrict__ fac) {
  __shared__ __align__(16) char lds[2 * 49152];
  gemm_body<1>(A, Bt, outp, nullptr, fac, lds);
}

// -------- phase projections pq/pk = xb @ Wpq / xb @ Wpk --------
__global__ __launch_bounds__(256) void k_phase_proj(const u16* __restrict__ xb,
                                                    const float* __restrict__ Wpq,
                                                    const float* __restrict__ Wpk,
                                                    float* __restrict__ pq,
                                                    float* __restrict__ pk) {
  __shared__ u16 xs[16][136];
  __shared__ float2 ws[128][16];
  const int t = threadIdx.x;
  const int m0 = blockIdx.x * 16;
  const int h = t & 15, r = t >> 4;
  float sq = 0.f, sk = 0.f;
  for (int kc = 0; kc < D_DIM; kc += 128) {
    *reinterpret_cast<short8*>(&xs[t >> 4][(t & 15) * 8]) =
        *reinterpret_cast<const short8*>(
            &xb[(size_t)(m0 + (t >> 4)) * D_DIM + kc + (t & 15) * 8]);
#pragma unroll
    for (int j = 0; j < 8; j++) {
      const int idx = j * 256 + t;
      const int k = idx >> 4, hh = idx & 15;
      ws[k][hh] = make_float2(Wpq[(size_t)(kc + k) * NHEAD + hh],
                              Wpk[(size_t)(kc + k) * NHEAD + hh]);
    }
    __syncthreads();
#pragma unroll
    for (int k8 = 0; k8 < 16; k8++) {
      const short8 x8 = *reinterpret_cast<const short8*>(&xs[r][k8 * 8]);
#pragma unroll
      for (int j = 0; j < 8; j++) {
        union { float f; unsigned u; } c;
        c.u = ((unsigned)(u16)x8[j]) << 16;
        const float2 wv = ws[k8 * 8 + j][h];
        sq += c.f * wv.x;
        sk += c.f * wv.y;
      }
    }
    __syncthreads();
  }
  pq[(size_t)(m0 + r) * NHEAD + h] = sq;
  pk[(size_t)(m0 + r) * NHEAD + h] = sk;
}

__device__ __forceinline__ float wave_sum(float v) {
  v += __shfl_xor(v, 1);  v += __shfl_xor(v, 2);  v += __shfl_xor(v, 4);
  v += __shfl_xor(v, 8);  v += __shfl_xor(v, 16); v += __shfl_xor(v, 32);
  return v;
}

// -------- Ck/Sk = sum_s cos/sin(pk) per (b,h) --------
__global__ void k_phase_ck(const float* __restrict__ pk, float* __restrict__ Ck,
                           float* __restrict__ Sk) {
  int bh = blockIdx.x, b = bh >> 4, h = bh & 15;
  float c = 0.f, s = 0.f;
  for (int ss = threadIdx.x; ss < S_LEN; ss += 256) {
    float v = pk[((size_t)b * S_LEN + ss) * NHEAD + h];
    c += cosf(v); s += sinf(v);
  }
  c = wave_sum(c); s = wave_sum(s);
  __shared__ float rc[4], rs[4];
  int wv = threadIdx.x >> 6;
  if ((threadIdx.x & 63) == 0) { rc[wv] = c; rs[wv] = s; }
  __syncthreads();
  if (threadIdx.x == 0) {
    Ck[bh] = rc[0] + rc[1] + rc[2] + rc[3];
    Sk[bh] = rs[0] + rs[1] + rs[2] + rs[3];
  }
}

// -------- phase factor fac[m] = 1 + 0.1*phase_mod[m] (premultiplied) --------
__global__ void k_phase_mod(const float* __restrict__ pq, const float* __restrict__ Ck,
                            const float* __restrict__ Sk, float* __restrict__ pm) {
  int m = blockIdx.x * 256 + threadIdx.x;
  int b = m >> 11;
  float a = 0.f;
#pragma unroll
  for (int h = 0; h < NHEAD; h++) {
    float v = pq[(size_t)m * NHEAD + h];
    a += cosf(v) * Ck[b * NHEAD + h] + sinf(v) * Sk[b * NHEAD + h];
  }
  pm[m] = 1.0f + 0.1f * (a * (1.0f / (S_LEN * NHEAD)));
}

// -------- causal flash attention: R5-proven serial-staged loop --------
// 512 blocks (32x16), pairing g = gy<8 ? 15-gy : gy-8 (per-CU work uniform),
// 4 warps x 32 q-rows, 2 blocks/CU. Single 32KB K/V buffer; per tile:
// stage -> __syncthreads (implicit vmcnt drain) -> compute -> __syncthreads.
// exp2-domain softmax, T13 defer-max (band 11.0 log2), interior fast path.
__global__ __launch_bounds__(256, 2) void k_attn(const u16* __restrict__ Q,
                                                 const u16* __restrict__ K,
                                                 const u16* __restrict__ Vt,
                                                 u16* __restrict__ ctx) {
  const int bh = blockIdx.x;
  const int gy = blockIdx.y;
  const int g = (gy < 8) ? (15 - gy) : (gy - 8);
  const int b = bh >> 4, h = bh & 15;
  const int t = threadIdx.x;
  const int w = t >> 6, l = t & 63;
  const int ln = l & 31, hi = l >> 5;
  const int q0w = g * 128 + w * 32;
  const int qq = q0w + ln;
  const float sc2 = 0.08838834764831845f * 1.4426950408889634f;

  const u16* Qp = Q + (size_t)bh * S_LEN * HDIM;
  const char* Kg = (const char*)(K + (size_t)bh * S_LEN * HDIM);
  const char* Vg = (const char*)(Vt + (size_t)bh * HDIM * S_LEN);

  __shared__ __align__(16) char Ks[16384];
  __shared__ __align__(16) char Vs[16384];

  auto stage = [&](int t64) {
    const int k0 = t64 * 64;
#pragma unroll
    for (int i = 0; i < 4; i++) {
      const int key = i * 16 + w * 4 + (l >> 4);
      async16(Ks + i * 4096 + w * 1024,
              Kg + (size_t)(k0 + key) * 256 + (((l & 15) * 16) ^ ((key & 15) << 4)));
      const int d = i * 32 + w * 8 + (l >> 3);
      async16(Vs + i * 4096 + w * 1024,
              Vg + (size_t)d * (S_LEN * 2) + k0 * 2 + (((l & 7) * 16) ^ ((d & 7) << 4)));
    }
  };

  short8 qf[8];
#pragma unroll
  for (int c = 0; c < 8; c++)
    qf[c] = *reinterpret_cast<const short8*>(Qp + (size_t)qq * HDIM + c * 16 + hi * 8);

  f32x16 o[4];
#pragma unroll
  for (int ds = 0; ds < 4; ds++)
#pragma unroll
    for (int r = 0; r < 16; r++) o[ds][r] = 0.f;
  float mrun = -1e30f, lsum = 0.f;

  const int nt = (g + 1) * 2;
  for (int t64 = 0; t64 < nt; t64++) {
    const int k0 = t64 * 64;
    stage(t64);
    __syncthreads();
    if (k0 < q0w + 32) {
      f32x16 s[2];
#pragma unroll
      for (int ks = 0; ks < 2; ks++)
#pragma unroll
        for (int r = 0; r < 16; r++) s[ks][r] = 0.f;
      __builtin_amdgcn_s_setprio(1);
#pragma unroll
      for (int ks = 0; ks < 2; ks++) {
        const int key = ks * 32 + ln;
        const char* kb = Ks + key * 256;
        const unsigned swzk = (unsigned)((key & 15) << 4);
#pragma unroll
        for (int c = 0; c < 8; c++) {
          const short8 kf = *reinterpret_cast<const short8*>(
              kb + (((unsigned)(c * 32 + hi * 16)) ^ swzk));
          s[ks] = MFMA32(kf, qf[c], s[ks]);
        }
      }
      __builtin_amdgcn_s_setprio(0);
      float p[32];
      float mx = -1e30f;
      const bool interior = (k0 + 64 <= q0w + 1);
      if (interior) {
#pragma unroll
        for (int ks = 0; ks < 2; ks++)
#pragma unroll
          for (int r = 0; r < 16; r++) {
            const float v = s[ks][r] * sc2;
            p[ks * 16 + r] = v;
            mx = fmaxf(mx, v);
          }
      } else {
#pragma unroll
        for (int ks = 0; ks < 2; ks++)
#pragma unroll
          for (int r = 0; r < 16; r++) {
            const int key = k0 + ks * 32 + (r & 3) + 8 * (r >> 2) + 4 * hi;
            const float v = (key <= qq) ? s[ks][r] * sc2 : -1e30f;
            p[ks * 16 + r] = v;
            mx = fmaxf(mx, v);
          }
      }
      mx = fmaxf(mx, __shfl_xor(mx, 32));
      if (!__all(mx <= mrun + 11.0f)) {
        const float nm = fmaxf(mrun, mx);
        const float f = exp2f(mrun - nm);
        lsum *= f;
#pragma unroll
        for (int ds = 0; ds < 4; ds++)
#pragma unroll
          for (int r = 0; r < 16; r++) o[ds][r] *= f;
        mrun = nm;
      }
      float rs = 0.f;
#pragma unroll
      for (int i = 0; i < 32; i++) { p[i] = exp2f(p[i] - mrun); rs += p[i]; }
      rs += __shfl_xor(rs, 32);
      lsum += rs;
      short8 bfr[4];
#pragma unroll
      for (int sub = 0; sub < 2; sub++) {
#pragma unroll
        for (int half = 0; half < 2; half++) {
          const int pb = sub * 16 + half * 8;
          unsigned X1 = cvtpk(p[pb + 0], p[pb + 1]);
          unsigned X2 = cvtpk(p[pb + 2], p[pb + 3]);
          unsigned Y1 = cvtpk(p[pb + 4], p[pb + 5]);
          unsigned Y2 = cvtpk(p[pb + 6], p[pb + 7]);
          plswap(X1, Y1);
          plswap(X2, Y2);
          i32x4 bw;
          bw[0] = (int)X1; bw[1] = (int)X2; bw[2] = (int)Y1; bw[3] = (int)Y2;
          bfr[sub * 2 + half] = __builtin_bit_cast(short8, bw);
        }
      }
      __builtin_amdgcn_s_setprio(1);
#pragma unroll
      for (int ds = 0; ds < 4; ds++) {
        const int d = ds * 32 + ln;
        const char* vb = Vs + d * 128;
        const unsigned swzv = (unsigned)((d & 7) << 4);
#pragma unroll
        for (int slot = 0; slot < 4; slot++) {
          const short8 vf = *reinterpret_cast<const short8*>(
              vb + (((unsigned)(slot * 32 + hi * 16)) ^ swzv));
          o[ds] = MFMA32(vf, bfr[slot], o[ds]);
        }
      }
      __builtin_amdgcn_s_setprio(0);
    }
    __syncthreads();
  }

  const float rl = 1.0f / lsum;
#pragma unroll
  for (int ds = 0; ds < 4; ds++) {
#pragma unroll
    for (int rq = 0; rq < 4; rq++) {
      const int d = ds * 32 + 8 * rq + 4 * hi;
      ushort4 pk4;
      pk4.x = f2bf(o[ds][rq * 4 + 0] * rl);
      pk4.y = f2bf(o[ds][rq * 4 + 1] * rl);
      pk4.z = f2bf(o[ds][rq * 4 + 2] * rl);
      pk4.w = f2bf(o[ds][rq * 4 + 3] * rl);
      *reinterpret_cast<ushort4*>(ctx + ((size_t)(b * S_LEN + qq)) * D_DIM + h * HDIM + d) = pk4;
    }
  }
}

extern "C" void kernel_launch(void* const* d_in, const int* in_sizes, int n_in,
                              void* d_out, int out_size, void* d_ws, size_t ws_size,
                              hipStream_t stream) {
  const float* x   = (const float*)d_in[0];
  const float* Wq  = (const float*)d_in[1];
  const float* Wk  = (const float*)d_in[2];
  const float* Wv  = (const float*)d_in[3];
  const float* Wo  = (const float*)d_in[4];
  const float* Wpq = (const float*)d_in[5];
  const float* Wpk = (const float*)d_in[6];

  char* ws = (char*)d_ws;
  u16* xb   = (u16*)(ws + 0);
  u16* Wqt  = (u16*)(ws + 16777216);
  u16* Wkt  = (u16*)(ws + 25165824);
  u16* Wvt  = (u16*)(ws + 33554432);
  u16* Wot  = (u16*)(ws + 41943040);
  u16* Qb   = (u16*)(ws + 50331648);
  u16* Kb   = (u16*)(ws + 67108864);
  u16* Vb   = (u16*)(ws + 83886080);
  u16* Vt   = (u16*)(ws + 100663296);
  float* pq = (float*)(ws + 117440512);
  float* pk = (float*)(ws + 117702656);
  float* Ck = (float*)(ws + 117964800);
  float* Sk = (float*)(ws + 117964928);
  float* pm = (float*)(ws + 117965056);

  // fused prep: 4 weight transposes + x convert in one launch
  k_prep<<<dim3(64, 64, 6), 256, 0, stream>>>(Wq, Wk, Wv, Wo, Wqt, Wkt, Wvt, Wot, x, xb);

  // fused QKV: Bt = [Wqt;Wkt;Wvt] = [6144][2048], 128x256 tiles
  // grid 24x32 = 768 blocks -> 3 clean rounds; V written straight to Vt
  k_qkv<<<dim3(24, 32), 512, 0, stream>>>(xb, Wqt, Qb, Vt);

  k_phase_proj<<<dim3(256), 256, 0, stream>>>(xb, Wpq, Wpk, pq, pk);
  k_phase_ck<<<dim3(32), 256, 0, stream>>>(pk, Ck, Sk);
  k_phase_mod<<<dim3(16), 256, 0, stream>>>(pq, Ck, Sk, pm);

  // attention: 512 blocks, per-CU-paired uniform work, serial-staged loop
  k_attn<<<dim3(32, 16), 256, 0, stream>>>(Qb, Kb, Vt, Vb /*ctx*/);

  // O-proj: 128x256 tiles -> grid 8x32 = 256 blocks, one full round
  k_oproj<<<dim3(8, 32), 512, 0, stream>>>(Vb /*ctx*/, Wot, (void*)d_out, pm);
}

// Round 18
// 321.350 us; speedup vs baseline: 1.0175x; 1.0017x over previous
//
#include <hip/hip_runtime.h>
#include <hip/hip_bf16.h>

typedef __attribute__((ext_vector_type(8))) short short8;
typedef __attribute__((ext_vector_type(4))) float f32x4;
typedef __attribute__((ext_vector_type(16))) float f32x16;
typedef __attribute__((ext_vector_type(4))) int i32x4;
typedef unsigned short u16;

#define S_LEN 2048
#define D_DIM 2048
#define NHEAD 16
#define HDIM 128
#define M_ROWS 4096

#define MFMA(a,b,c) __builtin_amdgcn_mfma_f32_16x16x32_bf16(a,b,c,0,0,0)
#define MFMA32(a,b,c) __builtin_amdgcn_mfma_f32_32x32x16_bf16(a,b,c,0,0,0)

__device__ __forceinline__ u16 f2bf(float f) {
  union { float f; unsigned u; } v; v.f = f;
  unsigned r = v.u + 0x7fffu + ((v.u >> 16) & 1u);
  return (u16)(r >> 16);
}

__device__ __forceinline__ void async16(void* lds, const void* g) {
  __builtin_amdgcn_global_load_lds(
      (const __attribute__((address_space(1))) unsigned*)g,
      (__attribute__((address_space(3))) unsigned*)lds, 16, 0, 0);
}

__device__ __forceinline__ unsigned cvtpk(float lo, float hi) {
  unsigned r;
  asm("v_cvt_pk_bf16_f32 %0, %1, %2" : "=v"(r) : "v"(lo), "v"(hi));
  return r;
}
__device__ __forceinline__ void plswap(unsigned& x, unsigned& y) {
  asm("v_permlane32_swap_b32 %0, %1" : "+v"(x), "+v"(y));
}

// ---- fused prep: z<4 -> transpose+convert W_z; z=4,5 -> convert x ----
__global__ __launch_bounds__(256) void k_prep(const float* __restrict__ W0,
                                              const float* __restrict__ W1,
                                              const float* __restrict__ W2,
                                              const float* __restrict__ W3,
                                              u16* __restrict__ T0, u16* __restrict__ T1,
                                              u16* __restrict__ T2, u16* __restrict__ T3,
                                              const float* __restrict__ x,
                                              u16* __restrict__ xb) {
  const int z = blockIdx.z;
  if (z < 4) {
    __shared__ u16 tile[32][33];
    const float* W = (z == 0) ? W0 : (z == 1) ? W1 : (z == 2) ? W2 : W3;
    u16* Wt = (z == 0) ? T0 : (z == 1) ? T1 : (z == 2) ? T2 : T3;
    int n0 = blockIdx.x * 32, k0 = blockIdx.y * 32;
    int tx = threadIdx.x & 31, ty = threadIdx.x >> 5;
#pragma unroll
    for (int i = 0; i < 4; i++)
      tile[ty + i * 8][tx] = f2bf(W[(size_t)(k0 + ty + i * 8) * D_DIM + n0 + tx]);
    __syncthreads();
#pragma unroll
    for (int i = 0; i < 4; i++)
      Wt[(size_t)(n0 + ty + i * 8) * D_DIM + k0 + tx] = tile[tx][ty + i * 8];
  } else {
    const int row0 = (z - 4) * 2048 + blockIdx.y * 32;
    const int col0 = blockIdx.x * 32;
    const int r = threadIdx.x >> 3, c4 = threadIdx.x & 7;
    const float4 v = *reinterpret_cast<const float4*>(
        &x[(size_t)(row0 + r) * D_DIM + col0 + c4 * 4]);
    ushort4 o;
    o.x = f2bf(v.x); o.y = f2bf(v.y); o.z = f2bf(v.z); o.w = f2bf(v.w);
    *reinterpret_cast<ushort4*>(&xb[(size_t)(row0 + r) * D_DIM + col0 + c4 * 4]) = o;
  }
}

// ======== 4-phase dbuf GEMM (R9/R16-proven): C = A[M][K] * Bt[N][K]^T ========
// Tile 128x256, BK=64 (2 K-subs), 8 waves (2M x 4N), wave tile 64x64.
// Counted vmcnt {3,5,4} steady / {3,2,0} tail; 3 barriers/K-tile.
template <int MODE>
__device__ __forceinline__ void gemm_body(const u16* __restrict__ A,
                                          const u16* __restrict__ Bt,
                                          void* __restrict__ outp,
                                          u16* __restrict__ Vt,
                                          const float* __restrict__ fac,
                                          char* lds) {
  constexpr int BUFSZ = 49152;  // A 2x8KB + B 2x16KB
  const int m0 = blockIdx.y * 128, n0 = blockIdx.x * 256;
  const int t = threadIdx.x;
  const int w = t >> 6, l = t & 63;
  const int wr = (w >> 2) * 64, wc = (w & 3) * 64;
  const int lr = l & 15, lq = l >> 4;
  const char* Ab = (const char*)A;
  const char* Bb = (const char*)Bt;

  f32x4 acc[4][4] = {};

  const int sub = w >> 2, ww = w & 3;
  const int abase = (ww & 1) * 16 + (ww >> 1) * 64;
  const int bbase = (w >> 1) * 64 + (w & 1) * 16;
  const int rr = l >> 2, sl = l & 3;

  auto stageA = [&](int tt, int nb, int mh) {
    const int base = abase + mh * 32;
    const int row = base + rr;
    async16(lds + nb * BUFSZ + sub * 8192 + base * 64,
            Ab + (size_t)(m0 + row) * 4096 + tt * 128 + sub * 64 +
                ((sl ^ ((row >> 1) & 3)) * 16));
  };
  auto stageB = [&](int tt, int nb, int nh) {
    const int base = bbase + nh * 32;
    const int row = base + rr;
#pragma unroll
    for (int j = 0; j < 2; j++)
      async16(lds + nb * BUFSZ + 16384 + j * 16384 + base * 64,
              Bb + (size_t)(n0 + row) * 4096 + tt * 128 + j * 64 +
                  ((sl ^ ((row >> 1) & 3)) * 16));
  };

  auto readA = [&](short8 af[2][2], int buf, int mh) {
#pragma unroll
    for (int mi = 0; mi < 2; mi++)
#pragma unroll
      for (int ks = 0; ks < 2; ks++) {
        const int row = wr + mh * 32 + mi * 16 + lr;
        af[mi][ks] = *reinterpret_cast<const short8*>(
            lds + buf * BUFSZ + ks * 8192 + row * 64 +
            ((lq ^ ((row >> 1) & 3)) * 16));
      }
  };
  auto readB = [&](short8 bf[2][2], int buf, int nh) {
#pragma unroll
    for (int ni = 0; ni < 2; ni++)
#pragma unroll
      for (int ks = 0; ks < 2; ks++) {
        const int row = wc + nh * 32 + ni * 16 + lr;
        bf[ni][ks] = *reinterpret_cast<const short8*>(
            lds + buf * BUFSZ + 16384 + ks * 16384 + row * 64 +
            ((lq ^ ((row >> 1) & 3)) * 16));
      }
  };

#define QUAD(AF, BF, MH, NH)                                                \
  {                                                                         \
    __builtin_amdgcn_s_setprio(1);                                          \
    _Pragma("unroll") for (int mi = 0; mi < 2; mi++)                        \
    _Pragma("unroll") for (int ni = 0; ni < 2; ni++)                        \
    _Pragma("unroll") for (int ks = 0; ks < 2; ks++)                        \
      acc[(MH)*2 + mi][(NH)*2 + ni] =                                       \
          MFMA(AF[mi][ks], BF[ni][ks], acc[(MH)*2 + mi][(NH)*2 + ni]);      \
    __builtin_amdgcn_s_setprio(0);                                          \
  }
#define VMW(N) asm volatile("s_waitcnt vmcnt(" #N ")" ::: "memory")
#define BAR()                         \
  do {                                \
    __builtin_amdgcn_s_barrier();     \
    asm volatile("" ::: "memory");    \
  } while (0)

  // prologue: u0, u1, u2 of tile 0 -> buf 0 (6 loads)
  stageA(0, 0, 0); stageB(0, 0, 0);
  stageA(0, 0, 1);
  stageB(0, 0, 1);

  short8 af0[2][2], af1[2][2], bfr[2][2];
  const int NT = D_DIM / 64;  // 32
  for (int tt = 0; tt < NT; tt++) {
    const int buf = tt & 1, nb = buf ^ 1;
    const bool pf = (tt + 1 < NT);
    // phase 0: (0,0); needs u0(t); stage u0(t+1)
    VMW(3); BAR();
    if (pf) { stageA(tt + 1, nb, 0); stageB(tt + 1, nb, 0); }
    readA(af0, buf, 0); readB(bfr, buf, 0);
    QUAD(af0, bfr, 0, 0);
    // phase 1: (1,0); needs u1(t); stage u1(t+1)
    if (pf) VMW(5); else VMW(2);
    BAR();
    if (pf) stageA(tt + 1, nb, 1);
    readA(af1, buf, 1);
    QUAD(af1, bfr, 1, 0);
    // phase 2: (1,1); needs u2(t); stage u2(t+1)
    if (pf) VMW(4); else VMW(0);
    BAR();
    if (pf) stageB(tt + 1, nb, 1);
    readB(bfr, buf, 1);
    QUAD(af1, bfr, 1, 1);
    // phase 3: (0,1); pure-register MFMA — next tile-top VMW+BAR closes window
    QUAD(af0, bfr, 0, 1);
  }
#undef QUAD
#undef VMW
#undef BAR

  // epilogue
#pragma unroll
  for (int gm = 0; gm < 4; gm++) {
#pragma unroll
    for (int gn = 0; gn < 4; gn++) {
      const int row0 = m0 + wr + gm * 16 + lq * 4;
      const int col = n0 + wc + gn * 16 + lr;
      if (MODE == 0) {
        if (col >= 4096) {  // V -> Vt[b,h,d,s] direct
          const int d = col & 127, hh = (col >> 7) & 15;
          const int bb = row0 >> 11, s0 = row0 & 2047;
          ushort4 v4;
          v4.x = f2bf(acc[gm][gn][0]);
          v4.y = f2bf(acc[gm][gn][1]);
          v4.z = f2bf(acc[gm][gn][2]);
          v4.w = f2bf(acc[gm][gn][3]);
          *reinterpret_cast<ushort4*>(
              Vt + (((size_t)(bb * NHEAD + hh) * HDIM + d) * S_LEN + s0)) = v4;
        } else {
#pragma unroll
          for (int r = 0; r < 4; r++) {
            const int row = row0 + r;
            const int mat = col >> 11;
            const int hh = (col >> 7) & 15;
            ((u16*)outp)[(size_t)mat * 8388608 +
                         (((size_t)((row >> 11) * NHEAD + hh)) * S_LEN + (row & 2047)) * HDIM +
                         (col & 127)] = f2bf(acc[gm][gn][r]);
          }
        }
      } else {
#pragma unroll
        for (int r = 0; r < 4; r++) {
          const int row = row0 + r;
          ((float*)outp)[(size_t)row * D_DIM + col] = acc[gm][gn][r] * fac[row];
        }
      }
    }
  }
}

__global__ __launch_bounds__(512, 1) void k_qkv(const u16* __restrict__ A,
                                                const u16* __restrict__ Bt,
                                                void* __restrict__ outp,
                                                u16* __restrict__ Vt) {
  __shared__ __align__(16) char lds[2 * 49152];
  gemm_body<0>(A, Bt, outp, Vt, nullptr, lds);
}

__global__ __launch_bounds__(512, 1) void k_oproj(const u16* __restrict__ A,
                                                  const u16* __restrict__ Bt,
                                                  void* __restrict__ outp,
                                                  const float* __restrict__ fac) {
  __shared__ __align__(16) char lds[2 * 49152];
  gemm_body<1>(A, Bt, outp, nullptr, fac, lds);
}

// -------- phase projections pq/pk = xb @ Wpq / xb @ Wpk --------
__global__ __launch_bounds__(256) void k_phase_proj(const u16* __restrict__ xb,
                                                    const float* __restrict__ Wpq,
                                                    const float* __restrict__ Wpk,
                                                    float* __restrict__ pq,
                                                    float* __restrict__ pk) {
  __shared__ u16 xs[16][136];
  __shared__ float2 ws[128][16];
  const int t = threadIdx.x;
  const int m0 = blockIdx.x * 16;
  const int h = t & 15, r = t >> 4;
  float sq = 0.f, sk = 0.f;
  for (int kc = 0; kc < D_DIM; kc += 128) {
    *reinterpret_cast<short8*>(&xs[t >> 4][(t & 15) * 8]) =
        *reinterpret_cast<const short8*>(
            &xb[(size_t)(m0 + (t >> 4)) * D_DIM + kc + (t & 15) * 8]);
#pragma unroll
    for (int j = 0; j < 8; j++) {
      const int idx = j * 256 + t;
      const int k = idx >> 4, hh = idx & 15;
      ws[k][hh] = make_float2(Wpq[(size_t)(kc + k) * NHEAD + hh],
                              Wpk[(size_t)(kc + k) * NHEAD + hh]);
    }
    __syncthreads();
#pragma unroll
    for (int k8 = 0; k8 < 16; k8++) {
      const short8 x8 = *reinterpret_cast<const short8*>(&xs[r][k8 * 8]);
#pragma unroll
      for (int j = 0; j < 8; j++) {
        union { float f; unsigned u; } c;
        c.u = ((unsigned)(u16)x8[j]) << 16;
        const float2 wv = ws[k8 * 8 + j][h];
        sq += c.f * wv.x;
        sk += c.f * wv.y;
      }
    }
    __syncthreads();
  }
  pq[(size_t)(m0 + r) * NHEAD + h] = sq;
  pk[(size_t)(m0 + r) * NHEAD + h] = sk;
}

__device__ __forceinline__ float wave_sum(float v) {
  v += __shfl_xor(v, 1);  v += __shfl_xor(v, 2);  v += __shfl_xor(v, 4);
  v += __shfl_xor(v, 8);  v += __shfl_xor(v, 16); v += __shfl_xor(v, 32);
  return v;
}

// -------- Ck/Sk = sum_s cos/sin(pk) per (b,h) --------
__global__ void k_phase_ck(const float* __restrict__ pk, float* __restrict__ Ck,
                           float* __restrict__ Sk) {
  int bh = blockIdx.x, b = bh >> 4, h = bh & 15;
  float c = 0.f, s = 0.f;
  for (int ss = threadIdx.x; ss < S_LEN; ss += 256) {
    float v = pk[((size_t)b * S_LEN + ss) * NHEAD + h];
    c += cosf(v); s += sinf(v);
  }
  c = wave_sum(c); s = wave_sum(s);
  __shared__ float rc[4], rs[4];
  int wv = threadIdx.x >> 6;
  if ((threadIdx.x & 63) == 0) { rc[wv] = c; rs[wv] = s; }
  __syncthreads();
  if (threadIdx.x == 0) {
    Ck[bh] = rc[0] + rc[1] + rc[2] + rc[3];
    Sk[bh] = rs[0] + rs[1] + rs[2] + rs[3];
  }
}

// -------- phase factor fac[m] = 1 + 0.1*phase_mod[m] (premultiplied) --------
__global__ void k_phase_mod(const float* __restrict__ pq, const float* __restrict__ Ck,
                            const float* __restrict__ Sk, float* __restrict__ pm) {
  int m = blockIdx.x * 256 + threadIdx.x;
  int b = m >> 11;
  float a = 0.f;
#pragma unroll
  for (int h = 0; h < NHEAD; h++) {
    float v = pq[(size_t)m * NHEAD + h];
    a += cosf(v) * Ck[b * NHEAD + h] + sinf(v) * Sk[b * NHEAD + h];
  }
  pm[m] = 1.0f + 0.1f * (a * (1.0f / (S_LEN * NHEAD)));
}

// -------- causal flash attention: serial-staged loop, KVBLK=128 --------
// 512 blocks (32x16), pairing g = gy<8 ? 15-gy : gy-8, 4 warps x 32 q-rows,
// 2 blocks/CU (64KB LDS x 2 = 128KB). KVBLK=128: one stage+drain covers TWO
// 64-key compute halves -> serial iterations per CU halved (34 -> 17).
// K rows 256B, swizzle (key&15)<<4; V rows 256B (128 keys), swizzle
// (d&7)<<4 (bits 6:4 only, half-bit 7 preserved). exp2 softmax, T13
// defer-max (band 11.0 log2), interior fast path.
__global__ __launch_bounds__(256, 2) void k_attn(const u16* __restrict__ Q,
                                                 const u16* __restrict__ K,
                                                 const u16* __restrict__ Vt,
                                                 u16* __restrict__ ctx) {
  const int bh = blockIdx.x;
  const int gy = blockIdx.y;
  const int g = (gy < 8) ? (15 - gy) : (gy - 8);
  const int b = bh >> 4, h = bh & 15;
  const int t = threadIdx.x;
  const int w = t >> 6, l = t & 63;
  const int ln = l & 31, hi = l >> 5;
  const int q0w = g * 128 + w * 32;
  const int qq = q0w + ln;
  const float sc2 = 0.08838834764831845f * 1.4426950408889634f;

  const u16* Qp = Q + (size_t)bh * S_LEN * HDIM;
  const char* Kg = (const char*)(K + (size_t)bh * S_LEN * HDIM);
  const char* Vg = (const char*)(Vt + (size_t)bh * HDIM * S_LEN);

  __shared__ __align__(16) char Ks[32768];  // 128 keys x 256B
  __shared__ __align__(16) char Vs[32768];  // 128 d-rows x 256B (128 keys)

  auto stage = [&](int t128) {
    const int k0 = t128 * 128;
#pragma unroll
    for (int i = 0; i < 8; i++) {
      const int key = i * 16 + w * 4 + (l >> 4);
      async16(Ks + i * 4096 + w * 1024,
              Kg + (size_t)(k0 + key) * 256 + (((l & 15) * 16) ^ ((key & 15) << 4)));
      const int d = i * 16 + w * 4 + (l >> 4);
      async16(Vs + i * 4096 + w * 1024,
              Vg + (size_t)d * (S_LEN * 2) + k0 * 2 + (((l & 15) * 16) ^ ((d & 7) << 4)));
    }
  };

  short8 qf[8];
#pragma unroll
  for (int c = 0; c < 8; c++)
    qf[c] = *reinterpret_cast<const short8*>(Qp + (size_t)qq * HDIM + c * 16 + hi * 8);

  f32x16 o[4];
#pragma unroll
  for (int ds = 0; ds < 4; ds++)
#pragma unroll
    for (int r = 0; r < 16; r++) o[ds][r] = 0.f;
  float mrun = -1e30f, lsum = 0.f;

  const int nt = g + 1;  // 128-key tiles
  for (int t128 = 0; t128 < nt; t128++) {
    stage(t128);
    __syncthreads();  // drains DMA (compiler-inserted vmcnt(0))
#pragma unroll
    for (int half = 0; half < 2; half++) {
      const int k0 = t128 * 128 + half * 64;
      if (k0 >= q0w + 32) continue;  // warp-uniform skip
      f32x16 s[2];
#pragma unroll
      for (int ks = 0; ks < 2; ks++)
#pragma unroll
        for (int r = 0; r < 16; r++) s[ks][r] = 0.f;
      __builtin_amdgcn_s_setprio(1);
#pragma unroll
      for (int ks = 0; ks < 2; ks++) {
        const char* kb = Ks + (half * 64 + ks * 32 + ln) * 256;
        const unsigned swzk = (unsigned)((ln & 15) << 4);
#pragma unroll
        for (int c = 0; c < 8; c++) {
          const short8 kf = *reinterpret_cast<const short8*>(
              kb + (((unsigned)(c * 32 + hi * 16)) ^ swzk));
          s[ks] = MFMA32(kf, qf[c], s[ks]);
        }
      }
      __builtin_amdgcn_s_setprio(0);
      float p[32];
      float mx = -1e30f;
      const bool interior = (k0 + 64 <= q0w + 1);
      if (interior) {
#pragma unroll
        for (int ks = 0; ks < 2; ks++)
#pragma unroll
          for (int r = 0; r < 16; r++) {
            const float v = s[ks][r] * sc2;
            p[ks * 16 + r] = v;
            mx = fmaxf(mx, v);
          }
      } else {
#pragma unroll
        for (int ks = 0; ks < 2; ks++)
#pragma unroll
          for (int r = 0; r < 16; r++) {
            const int key = k0 + ks * 32 + (r & 3) + 8 * (r >> 2) + 4 * hi;
            const float v = (key <= qq) ? s[ks][r] * sc2 : -1e30f;
            p[ks * 16 + r] = v;
            mx = fmaxf(mx, v);
          }
      }
      mx = fmaxf(mx, __shfl_xor(mx, 32));
      if (!__all(mx <= mrun + 11.0f)) {
        const float nm = fmaxf(mrun, mx);
        const float f = exp2f(mrun - nm);
        lsum *= f;
#pragma unroll
        for (int ds = 0; ds < 4; ds++)
#pragma unroll
          for (int r = 0; r < 16; r++) o[ds][r] *= f;
        mrun = nm;
      }
      float rs = 0.f;
#pragma unroll
      for (int i = 0; i < 32; i++) { p[i] = exp2f(p[i] - mrun); rs += p[i]; }
      rs += __shfl_xor(rs, 32);
      lsum += rs;
      short8 bfr[4];
#pragma unroll
      for (int sub = 0; sub < 2; sub++) {
#pragma unroll
        for (int hf = 0; hf < 2; hf++) {
          const int pb = sub * 16 + hf * 8;
          unsigned X1 = cvtpk(p[pb + 0], p[pb + 1]);
          unsigned X2 = cvtpk(p[pb + 2], p[pb + 3]);
          unsigned Y1 = cvtpk(p[pb + 4], p[pb + 5]);
          unsigned Y2 = cvtpk(p[pb + 6], p[pb + 7]);
          plswap(X1, Y1);
          plswap(X2, Y2);
          i32x4 bw;
          bw[0] = (int)X1; bw[1] = (int)X2; bw[2] = (int)Y1; bw[3] = (int)Y2;
          bfr[sub * 2 + hf] = __builtin_bit_cast(short8, bw);
        }
      }
      __builtin_amdgcn_s_setprio(1);
#pragma unroll
      for (int ds = 0; ds < 4; ds++) {
        const int d = ds * 32 + ln;
        const char* vb = Vs + d * 256;
        const unsigned swzv = (unsigned)((d & 7) << 4);
#pragma unroll
        for (int slot = 0; slot < 4; slot++) {
          const short8 vf = *reinterpret_cast<const short8*>(
              vb + (((unsigned)(half * 128 + slot * 32 + hi * 16)) ^ swzv));
          o[ds] = MFMA32(vf, bfr[slot], o[ds]);
        }
      }
      __builtin_amdgcn_s_setprio(0);
    }
    __syncthreads();  // protect LDS before next stage
  }

  const float rl = 1.0f / lsum;
#pragma unroll
  for (int ds = 0; ds < 4; ds++) {
#pragma unroll
    for (int rq = 0; rq < 4; rq++) {
      const int d = ds * 32 + 8 * rq + 4 * hi;
      ushort4 pk4;
      pk4.x = f2bf(o[ds][rq * 4 + 0] * rl);
      pk4.y = f2bf(o[ds][rq * 4 + 1] * rl);
      pk4.z = f2bf(o[ds][rq * 4 + 2] * rl);
      pk4.w = f2bf(o[ds][rq * 4 + 3] * rl);
      *reinterpret_cast<ushort4*>(ctx + ((size_t)(b * S_LEN + qq)) * D_DIM + h * HDIM + d) = pk4;
    }
  }
}

extern "C" void kernel_launch(void* const* d_in, const int* in_sizes, int n_in,
                              void* d_out, int out_size, void* d_ws, size_t ws_size,
                              hipStream_t stream) {
  const float* x   = (const float*)d_in[0];
  const float* Wq  = (const float*)d_in[1];
  const float* Wk  = (const float*)d_in[2];
  const float* Wv  = (const float*)d_in[3];
  const float* Wo  = (const float*)d_in[4];
  const float* Wpq = (const float*)d_in[5];
  const float* Wpk = (const float*)d_in[6];

  char* ws = (char*)d_ws;
  u16* xb   = (u16*)(ws + 0);
  u16* Wqt  = (u16*)(ws + 16777216);
  u16* Wkt  = (u16*)(ws + 25165824);
  u16* Wvt  = (u16*)(ws + 33554432);
  u16* Wot  = (u16*)(ws + 41943040);
  u16* Qb   = (u16*)(ws + 50331648);
  u16* Kb   = (u16*)(ws + 67108864);
  u16* Vb   = (u16*)(ws + 83886080);
  u16* Vt   = (u16*)(ws + 100663296);
  float* pq = (float*)(ws + 117440512);
  float* pk = (float*)(ws + 117702656);
  float* Ck = (float*)(ws + 117964800);
  float* Sk = (float*)(ws + 117964928);
  float* pm = (float*)(ws + 117965056);

  // fused prep: 4 weight transposes + x convert in one launch
  k_prep<<<dim3(64, 64, 6), 256, 0, stream>>>(Wq, Wk, Wv, Wo, Wqt, Wkt, Wvt, Wot, x, xb);

  // fused QKV: Bt = [Wqt;Wkt;Wvt] = [6144][2048], 128x256 tiles
  k_qkv<<<dim3(24, 32), 512, 0, stream>>>(xb, Wqt, Qb, Vt);

  k_phase_proj<<<dim3(256), 256, 0, stream>>>(xb, Wpq, Wpk, pq, pk);
  k_phase_ck<<<dim3(32), 256, 0, stream>>>(pk, Ck, Sk);
  k_phase_mod<<<dim3(16), 256, 0, stream>>>(pq, Ck, Sk, pm);

  // attention: 512 blocks, per-CU-paired uniform work, KVBLK=128
  k_attn<<<dim3(32, 16), 256, 0, stream>>>(Qb, Kb, Vt, Vb /*ctx*/);

  // O-proj: 128x256 tiles -> grid 8x32 = 256 blocks, one full round
  k_oproj<<<dim3(8, 32), 512, 0, stream>>>(Vb /*ctx*/, Wot, (void*)d_out, pm);
}